// Round 10
// baseline (2260.958 us; speedup 1.0000x reference)
//
#include <hip/hip_runtime.h>
#include <math.h>

// B=4, N=256, H=256, HEADS=4, DH=64, FF=1024, V=256, L=128, rows BN=1024
#define NB 256

typedef __attribute__((ext_vector_type(8))) short bf16x8;
typedef __attribute__((ext_vector_type(4))) float f32x4;

__device__ __forceinline__ unsigned short f2b(float f) {   // f32 -> bf16 RNE
    unsigned u = __float_as_uint(f);
    u += 0x7FFFu + ((u >> 16) & 1u);
    return (unsigned short)(u >> 16);
}
__device__ __forceinline__ unsigned pack2(float a, float b) {
    return (unsigned)f2b(a) | ((unsigned)f2b(b) << 16);
}
__device__ __forceinline__ bf16x8 as_frag(uint4 v) {
    union { uint4 u; bf16x8 f; } x; x.u = v; return x.f;
}
__device__ __forceinline__ bf16x8 ld_frag_f32(const float* p) {  // 8 f32 -> bf16x8
    const float4 v0 = *(const float4*)p;
    const float4 v1 = *(const float4*)(p + 4);
    union { unsigned u[4]; bf16x8 f; } x;
    x.u[0] = pack2(v0.x, v0.y); x.u[1] = pack2(v0.z, v0.w);
    x.u[2] = pack2(v1.x, v1.y); x.u[3] = pack2(v1.z, v1.w);
    return x.f;
}

// Branchless erf-based gelu (A&S 7.1.26, max abs err 1.5e-7).
__device__ __forceinline__ float gelu_f(float x) {
    const float y  = 0.70710678118654752f * x;
    const float ay = fabsf(y);
    const float t  = __builtin_amdgcn_rcpf(fmaf(0.3275911f, ay, 1.0f));
    float S = fmaf(t, 1.061405429f, -1.453152027f);
    S = fmaf(t, S, 1.421413741f);
    S = fmaf(t, S, -0.284496736f);
    S = fmaf(t, S, 0.254829592f);
    S = S * t;
    const float e = __expf(-ay * ay);
    const float E = fmaf(-S, e, 1.0f);
    return 0.5f * x * (1.0f + copysignf(E, y));
}

struct PrepEnt { const float* src; unsigned dstOff; int K; int N; unsigned tstart; };
struct PrepTab { int n; PrepEnt e[36]; };

struct MegaArgs {
    const float *z; const int *tok; const int *tt;
    const float *lp1w,*lp1b,*lp2w,*lp2b,*temb,*ttab,*tw,*tb,*pos;
    const float *qkvb,*ob,*ln1g,*ln1b,*f1b,*f2b,*ln2g,*ln2b;
    const float *gqb,*gkb,*gvb,*gsb,*gl1g,*gl1b,*gf1b,*gf2b,*gl2g,*gl2b;
    const float *nh1b,*nh2b,*eh1b,*eh2w,*eh2b;
    const float *sh1w,*sh1b,*sh2w,*sh2b;
    float *Hh,*QK,*AO,*T1,*HI,*HJ,*LAT,*TE,*A1,*SH;
    unsigned char* MASK; unsigned short* wt; unsigned* bar;
    float *out_node,*out_edge,*out_sz;
    PrepTab ptab;
};

// ---------------- device-scope grid barrier (all NB blocks co-resident) ----------------
__device__ __forceinline__ void gsync(unsigned* bar) {
    __syncthreads();
    if (threadIdx.x == 0) {
        __threadfence();
        unsigned g = __hip_atomic_load(bar + 1, __ATOMIC_RELAXED, __HIP_MEMORY_SCOPE_AGENT);
        unsigned a = __hip_atomic_fetch_add(bar, 1u, __ATOMIC_ACQ_REL, __HIP_MEMORY_SCOPE_AGENT);
        if (a == (unsigned)(NB - 1)) {
            __hip_atomic_store(bar, 0u, __ATOMIC_RELAXED, __HIP_MEMORY_SCOPE_AGENT);
            __hip_atomic_fetch_add(bar + 1, 1u, __ATOMIC_ACQ_REL, __HIP_MEMORY_SCOPE_AGENT);
        } else {
            while (__hip_atomic_load(bar + 1, __ATOMIC_ACQUIRE, __HIP_MEMORY_SCOPE_AGENT) == g)
                __builtin_amdgcn_s_sleep(4);
        }
    }
    __syncthreads();
}

// ---------------- phase bodies ----------------
__device__ void prep_tile(const PrepTab& tab, unsigned short* wt, int t, char* SMc)
{
    unsigned (*Tl)[36] = (unsigned(*)[36])SMc;
    int ei = 0;
    for (int i = 0; i < tab.n; ++i) if (tab.e[i].tstart <= (unsigned)t) ei = i;
    const PrepEnt E = tab.e[ei];
    const int tIdx = t - (int)E.tstart;
    const int ntn = E.N >> 6;
    const int kt = tIdx / ntn, nt = tIdx % ntn;
    const int tid = threadIdx.x;
    {
        const int r = tid >> 2, c = (tid & 3) * 16;
        const float* s = E.src + (size_t)(kt * 64 + r) * E.N + nt * 64 + c;
        unsigned o[8];
        #pragma unroll
        for (int q = 0; q < 4; ++q) {
            const float4 v = *(const float4*)(s + q * 4);
            o[q * 2 + 0] = pack2(v.x, v.y);
            o[q * 2 + 1] = pack2(v.z, v.w);
        }
        *(uint4*)&Tl[r][c / 2 + 0] = make_uint4(o[0], o[1], o[2], o[3]);
        *(uint4*)&Tl[r][c / 2 + 4] = make_uint4(o[4], o[5], o[6], o[7]);
    }
    __syncthreads();
    {
        const int rn = tid >> 2, ck = (tid & 3) * 16;
        const int sh = (rn & 1) * 16, hw = rn >> 1;
        unsigned o[8];
        #pragma unroll
        for (int s = 0; s < 8; ++s) {
            const unsigned lo = (Tl[ck + 2 * s][hw] >> sh) & 0xFFFFu;
            const unsigned hi = (Tl[ck + 2 * s + 1][hw] >> sh) & 0xFFFFu;
            o[s] = lo | (hi << 16);
        }
        unsigned short* d = wt + E.dstOff + (size_t)(nt * 64 + rn) * E.K + kt * 64 + ck;
        *(uint4*)(d + 0) = make_uint4(o[0], o[1], o[2], o[3]);
        *(uint4*)(d + 8) = make_uint4(o[4], o[5], o[6], o[7]);
    }
    __syncthreads();
}

// 32x32 MFMA tile (4 waves = 4 16x16 quadrants). No LDS.
// C fragment map: col = n0 + (lane&15), row = m0 + (lane>>4)*4 + reg.
__device__ void gd32_tile(const float* A, const unsigned short* Wt, const float* bias,
                          float* C, int K, int ldc, int act, int m0, int n0)
{
    const int tid = threadIdx.x;
    const int l = tid & 63, wid = tid >> 6;
    const int qm = wid & 1, qn = wid >> 1, lr = l & 15, lg = l >> 4;
    const float* ap = A + (size_t)(m0 + qm * 16 + lr) * K + lg * 8;
    const unsigned short* bp = Wt + (size_t)(n0 + qn * 16 + lr) * K + lg * 8;
    f32x4 acc = {0.f,0.f,0.f,0.f};
    #pragma unroll 4
    for (int k0 = 0; k0 < K; k0 += 32) {
        const bf16x8 fa = ld_frag_f32(ap + k0);
        const bf16x8 fb = as_frag(*(const uint4*)(bp + k0));
        acc = __builtin_amdgcn_mfma_f32_16x16x32_bf16(fa, fb, acc, 0, 0, 0);
    }
    const int cc = n0 + qn * 16 + lr;
    const float bv = bias ? bias[cc] : 0.f;
    #pragma unroll
    for (int r = 0; r < 4; ++r) {
        const int row = m0 + qm * 16 + lg * 4 + r;
        float v = acc[r] + bv;
        if (act == 1) v = fmaxf(v, 0.f); else if (act == 2) v = gelu_f(v);
        C[(size_t)row * ldc + cc] = v;
    }
}

// attention for one (b, head, 16-row group); blk in [0,256)
__device__ void attn_block(const float* qkv, int ld, int qo, int ko, int vo,
    const unsigned char* mask, float* outp, int blk, char* SMc)
{
    float (*Qs)[68]  = (float(*)[68])SMc;
    float (*Ts)[68]  = (float(*)[68])(SMc + 4352);
    float (*Ss)[260] = (float(*)[260])(SMc + 21760);
    const int ig = blk & 15, hh = (blk >> 4) & 3, b = blk >> 6;
    const int i0 = ig * 16;
    const int t = threadIdx.x;
    {
        const int r = t >> 4, c = (t & 15) * 4;
        *(float4*)&Qs[r][c] = *(const float4*)&qkv[(size_t)(b * 256 + i0 + r) * ld + qo + hh * 64 + c];
    }
    const int i = t >> 4, tx = t & 15;
    for (int jt = 0; jt < 4; ++jt) {
        __syncthreads();
        {
            const int jr = t >> 2, cs = (t & 3) * 16;
            const float* src = &qkv[(size_t)(b * 256 + jt * 64 + jr) * ld + ko + hh * 64 + cs];
            *(float4*)&Ts[jr][cs + 0]  = *(const float4*)(src + 0);
            *(float4*)&Ts[jr][cs + 4]  = *(const float4*)(src + 4);
            *(float4*)&Ts[jr][cs + 8]  = *(const float4*)(src + 8);
            *(float4*)&Ts[jr][cs + 12] = *(const float4*)(src + 12);
        }
        __syncthreads();
        float s0 = 0.f, s1 = 0.f, s2 = 0.f, s3 = 0.f;
        #pragma unroll 8
        for (int d = 0; d < 64; ++d) {
            const float qd = Qs[i][d];
            s0 += qd * Ts[tx][d];
            s1 += qd * Ts[tx + 16][d];
            s2 += qd * Ts[tx + 32][d];
            s3 += qd * Ts[tx + 48][d];
        }
        Ss[i][jt * 64 + tx]      = s0;
        Ss[i][jt * 64 + tx + 16] = s1;
        Ss[i][jt * 64 + tx + 32] = s2;
        Ss[i][jt * 64 + tx + 48] = s3;
    }
    {
        const unsigned char* mrow = mask ? &mask[(size_t)(b * 256 + i0 + i) * 256] : nullptr;
        float sv[16]; bool okv[16];
        float m = -3.0e38f;
        #pragma unroll
        for (int k = 0; k < 16; ++k) {
            const int j = tx + 16 * k;
            const float s = Ss[i][j] * 0.125f;
            const bool ok = mrow ? (mrow[j] != 0) : true;
            sv[k] = s; okv[k] = ok;
            if (ok) m = fmaxf(m, s);
        }
        #pragma unroll
        for (int w = 1; w < 16; w <<= 1) m = fmaxf(m, __shfl_xor(m, w, 64));
        float sum = 0.f;
        #pragma unroll
        for (int k = 0; k < 16; ++k) {
            sv[k] = okv[k] ? __expf(sv[k] - m) : 0.f;
            sum += sv[k];
        }
        #pragma unroll
        for (int w = 1; w < 16; w <<= 1) sum += __shfl_xor(sum, w, 64);
        const float inv = (sum > 0.f) ? 1.f / sum : 0.f;
        #pragma unroll
        for (int k = 0; k < 16; ++k) Ss[i][tx + 16 * k] = sv[k] * inv;
    }
    const int d4 = tx * 4;
    float4 o = {0.f, 0.f, 0.f, 0.f};
    for (int jt = 0; jt < 4; ++jt) {
        __syncthreads();
        {
            const int jr = t >> 2, cs = (t & 3) * 16;
            const float* src = &qkv[(size_t)(b * 256 + jt * 64 + jr) * ld + vo + hh * 64 + cs];
            *(float4*)&Ts[jr][cs + 0]  = *(const float4*)(src + 0);
            *(float4*)&Ts[jr][cs + 4]  = *(const float4*)(src + 4);
            *(float4*)&Ts[jr][cs + 8]  = *(const float4*)(src + 8);
            *(float4*)&Ts[jr][cs + 12] = *(const float4*)(src + 12);
        }
        __syncthreads();
        #pragma unroll 8
        for (int j = 0; j < 64; ++j) {
            const float p = Ss[i][jt * 64 + j];
            const float4 v4 = *(const float4*)&Ts[j][d4];
            o.x += p * v4.x; o.y += p * v4.y; o.z += p * v4.z; o.w += p * v4.w;
        }
    }
    *(float4*)&outp[(size_t)(b * 256 + i0 + i) * 256 + hh * 64 + d4] = o;
    __syncthreads();
}

// wave-per-row LN over 4 rows/block: out = LN(a + bb? + cc?) * g + beta
__device__ void ln_rows(const float* a, const float* bb, int ldb,
    const float* cc, int ldc, const float* g, const float* beta, float* outp, int bid)
{
    const int r = bid * 4 + (threadIdx.x >> 6);
    const int c4 = (threadIdx.x & 63) * 4;
    float4 v = *(const float4*)&a[(size_t)r * 256 + c4];
    if (bb) {
        const float4 u = *(const float4*)&bb[(size_t)r * ldb + c4];
        v.x += u.x; v.y += u.y; v.z += u.z; v.w += u.w;
    }
    if (cc) {
        const float4 u = *(const float4*)&cc[(size_t)r * ldc + c4];
        v.x += u.x; v.y += u.y; v.z += u.z; v.w += u.w;
    }
    float s = v.x + v.y + v.z + v.w;
    float q = v.x * v.x + v.y * v.y + v.z * v.z + v.w * v.w;
    #pragma unroll
    for (int w = 1; w < 64; w <<= 1) {
        s += __shfl_xor(s, w, 64);
        q += __shfl_xor(q, w, 64);
    }
    const float mean = s * (1.0f / 256.0f);
    const float var  = q * (1.0f / 256.0f) - mean * mean;
    const float inv  = rsqrtf(var + 1e-5f);
    const float4 gg = *(const float4*)&g[c4];
    const float4 be = *(const float4*)&beta[c4];
    float4 o;
    o.x = (v.x - mean) * inv * gg.x + be.x;
    o.y = (v.y - mean) * inv * gg.y + be.y;
    o.z = (v.z - mean) * inv * gg.z + be.z;
    o.w = (v.w - mean) * inv * gg.w + be.w;
    *(float4*)&outp[(size_t)r * 256 + c4] = o;
}

// one 16x16 edge tile
__device__ void edge_tile(const float* hi, const float* hj, const float* w2,
    const float* b2, float* val_out, unsigned char* mask_out,
    int b, int ig, int jg, char* SMc)
{
    float (*his)[268] = (float(*)[268])SMc;
    float (*hjs)[268] = (float(*)[268])(SMc + 17152);
    float* w2s = (float*)(SMc + 34304);
    const int t = threadIdx.x;
    {
        const int r = t >> 4, c = (t & 15) * 16;
        const float* s1 = &hi[(size_t)(b * 256 + ig * 16 + r) * 256 + c];
        const float* s2 = &hj[(size_t)(b * 256 + jg * 16 + r) * 256 + c];
        #pragma unroll
        for (int q = 0; q < 4; ++q) {
            *(float4*)&his[r][c + q * 4] = *(const float4*)(s1 + q * 4);
            *(float4*)&hjs[r][c + q * 4] = *(const float4*)(s2 + q * 4);
        }
        w2s[t] = w2[t];
    }
    __syncthreads();
    const int i = t >> 4, j = t & 15;
    float acc = 0.f;
    #pragma unroll 4
    for (int h4 = 0; h4 < 64; ++h4) {
        const float4 hv  = *(const float4*)&hjs[j][h4 * 4];
        const float4 hi4 = *(const float4*)&his[i][h4 * 4];
        const float4 w4  = *(const float4*)&w2s[h4 * 4];
        acc += gelu_f(hi4.x + hv.x) * w4.x;
        acc += gelu_f(hi4.y + hv.y) * w4.y;
        acc += gelu_f(hi4.z + hv.z) * w4.z;
        acc += gelu_f(hi4.w + hv.w) * w4.w;
    }
    const float v = acc + b2[0];
    if (val_out)  val_out[(size_t)b * 65536 + (ig * 16 + i) * 256 + jg * 16 + j] = v;
    if (mask_out) mask_out[(size_t)b * 65536 + (jg * 16 + j) * 256 + ig * 16 + i] =
                      (v > -0.84729786038720f) ? 1 : 0;
    __syncthreads();
}

// matvec chunk: out[rb, cb*64 .. +63] (256 thr = 64 cols x 4 K-slices)
__device__ void mv_chunk(const float* A, const int* aidx, int K, const float* Wm,
                         const float* bias, float* outp, int N, int act,
                         int rb, int cb, char* SMc)
{
    float (*red)[64] = (float(*)[64])SMc;
    const int c = threadIdx.x & 63, ks = threadIdx.x >> 6;
    const int c0 = cb * 64;
    const float* arow = A + (size_t)(aidx ? aidx[rb] : rb) * K;
    float s = 0.f;
    for (int k = ks; k < K; k += 4) s += arow[k] * Wm[(size_t)k * N + c0 + c];
    __syncthreads();
    red[ks][c] = s;
    __syncthreads();
    if (ks == 0) {
        float v = red[0][c] + red[1][c] + red[2][c] + red[3][c]
                + (bias ? bias[c0 + c] : 0.f);
        if (act == 1) v = fmaxf(v, 0.f); else if (act == 2) v = gelu_f(v);
        outp[(size_t)rb * N + c0 + c] = v;
    }
}

// ---------------- the mega kernel ----------------
__global__ __launch_bounds__(256) void k_mega(MegaArgs A)
{
    __shared__ __align__(16) char SM[38912];
    const int bid = blockIdx.x;
    const int tid = threadIdx.x;

    // P0: weight prep (1216 tiles)
    for (int t = bid; t < 1216; t += NB) prep_tile(A.ptab, A.wt, t, SM);
    gsync(A.bar);

    // S0: a1 (blocks 0-15), TE (blocks 16-31)
    if (bid < 16) mv_chunk(A.z, nullptr, 128, A.lp1w, A.lp1b, A.A1, 256, 1, bid >> 2, bid & 3, SM);
    else if (bid < 32) { const int b2 = bid - 16;
        mv_chunk(A.ttab, A.tt, 256, A.tw, A.tb, A.TE, 256, 2, b2 >> 2, b2 & 3, SM); }
    gsync(A.bar);

    // S1: LAT
    if (bid < 16) mv_chunk(A.A1, nullptr, 256, A.lp2w, A.lp2b, A.LAT, 256, 0, bid >> 2, bid & 3, SM);
    gsync(A.bar);

    // S2: embed (all blocks, 4 rows each) + SH (blocks 0-7)
    for (int q = 0; q < 4; ++q) {
        const int r = bid * 4 + q, b = r >> 8, n = r & 255;
        A.Hh[(size_t)r * 256 + tid] = A.temb[(size_t)A.tok[r] * 256 + tid] + A.TE[b * 256 + tid]
                                    + A.pos[n * 256 + tid] + A.LAT[b * 256 + tid];
    }
    if (bid < 8) mv_chunk(A.LAT, nullptr, 256, A.sh1w, A.sh1b, A.SH, 128, 1, bid >> 1, bid & 1, SM);
    gsync(A.bar);

    // ---- encoder x2 ----
    for (int l = 0; l < 2; ++l) {
        // qkv GEMM: 768 tiles (+ size head on l==0)
        for (int t = bid; t < 768; t += NB)
            gd32_tile(A.Hh, A.wt + (size_t)l * 196608, A.qkvb + l * 768, A.QK,
                      256, 768, 0, (t & 31) * 32, (t >> 5) * 32);
        if (l == 0 && bid < 16)
            mv_chunk(A.SH, nullptr, 128, A.sh2w, A.sh2b, A.out_sz, 256, 0, bid >> 2, bid & 3, SM);
        gsync(A.bar);
        attn_block(A.QK, 768, 0, 256, 512, nullptr, A.AO, bid, SM);
        gsync(A.bar);
        gd32_tile(A.AO, A.wt + 393216 + (size_t)l * 65536, A.ob + l * 256, A.T1,
                  256, 256, 0, (bid & 31) * 32, (bid >> 5) * 32);
        gsync(A.bar);
        ln_rows(A.Hh, A.T1, 256, nullptr, 0, A.ln1g + l * 256, A.ln1b + l * 256, A.Hh, bid);
        gsync(A.bar);
        for (int t = bid; t < 1024; t += NB)
            gd32_tile(A.Hh, A.wt + 524288 + (size_t)l * 262144, A.f1b + l * 1024, A.QK,
                      256, 1024, 1, (t & 31) * 32, (t >> 5) * 32);
        gsync(A.bar);
        gd32_tile(A.QK, A.wt + 1048576 + (size_t)l * 262144, A.f2b + l * 256, A.T1,
                  1024, 256, 0, (bid & 31) * 32, (bid >> 5) * 32);
        gsync(A.bar);
        ln_rows(A.Hh, A.T1, 256, nullptr, 0, A.ln2g + l * 256, A.ln2b + l * 256, A.Hh, bid);
        gsync(A.bar);
    }

    // ---- mask: HI/HJ (512 tiles) then edge->MASK (1024 tiles) ----
    for (int t = bid; t < 512; t += NB) {
        const int s = t & 255, tm = (s & 31) * 32, tn = (s >> 5) * 32;
        if (t < 256) gd32_tile(A.Hh, A.wt + 4849664, A.eh1b, A.HI, 256, 256, 0, tm, tn);
        else         gd32_tile(A.Hh, A.wt + 4915200, nullptr, A.HJ, 256, 256, 0, tm, tn);
    }
    gsync(A.bar);
    for (int t = bid; t < 1024; t += NB)
        edge_tile(A.HI, A.HJ, A.eh2w, A.eh2b, nullptr, A.MASK, t >> 8, (t >> 4) & 15, t & 15, SM);
    gsync(A.bar);

    // ---- GNN x4 ----
    for (int l = 0; l < 4; ++l) {
        for (int t = bid; t < 1024; t += NB) {
            const int which = t >> 8, s = t & 255;
            const unsigned short* w = A.wt + 1572864 + (size_t)which * 262144 + (size_t)l * 65536;
            const float* bi = (which == 0 ? A.gqb : which == 1 ? A.gkb :
                               which == 2 ? A.gvb : A.gsb) + l * 256;
            gd32_tile(A.Hh, w, bi, A.QK + which * 256, 256, 1024, 0,
                      (s & 31) * 32, (s >> 5) * 32);
        }
        gsync(A.bar);
        attn_block(A.QK, 1024, 0, 256, 512, A.MASK, A.AO, bid, SM);
        gsync(A.bar);
        ln_rows(A.Hh, A.AO, 256, A.QK + 768, 1024, A.gl1g + l * 256, A.gl1b + l * 256, A.Hh, bid);
        gsync(A.bar);
        for (int t = bid; t < 1024; t += NB)
            gd32_tile(A.Hh, A.wt + 2621440 + (size_t)l * 262144, A.gf1b + l * 1024, A.QK,
                      256, 1024, 2, (t & 31) * 32, (t >> 5) * 32);
        gsync(A.bar);
        gd32_tile(A.QK, A.wt + 3670016 + (size_t)l * 262144, A.gf2b + l * 256, A.T1,
                  1024, 256, 0, (bid & 31) * 32, (bid >> 5) * 32);
        gsync(A.bar);
        ln_rows(A.Hh, A.T1, 256, nullptr, 0, A.gl2g + l * 256, A.gl2b + l * 256, A.Hh, bid);
        gsync(A.bar);
    }

    // ---- heads: nh1/HI/HJ (768 tiles) ----
    for (int t = bid; t < 768; t += NB) {
        const int which = t >> 8, s = t & 255, tm = (s & 31) * 32, tn = (s >> 5) * 32;
        if (which == 0)      gd32_tile(A.Hh, A.wt + 4718592, A.nh1b, A.T1, 256, 256, 2, tm, tn);
        else if (which == 1) gd32_tile(A.Hh, A.wt + 4849664, A.eh1b, A.HI, 256, 256, 0, tm, tn);
        else                 gd32_tile(A.Hh, A.wt + 4915200, nullptr, A.HJ, 256, 256, 0, tm, tn);
    }
    gsync(A.bar);
    // final: nh2 (1 tile/block) + edge final (4 tiles/block)
    gd32_tile(A.T1, A.wt + 4784128, A.nh2b, A.out_node, 256, 256, 0,
              (bid & 31) * 32, (bid >> 5) * 32);
    for (int t = bid; t < 1024; t += NB)
        edge_tile(A.HI, A.HJ, A.eh2w, A.eh2b, A.out_edge, nullptr, t >> 8, (t >> 4) & 15, t & 15, SM);
}

extern "C" void kernel_launch(void* const* d_in, const int* in_sizes, int n_in,
                              void* d_out, int out_size, void* d_ws, size_t ws_size,
                              hipStream_t stream) {
    const float* z     = (const float*)d_in[0];
    const int*   tok   = (const int*)d_in[1];
    const int*   tt    = (const int*)d_in[2];
    const float* lp1w  = (const float*)d_in[3];
    const float* lp1b  = (const float*)d_in[4];
    const float* lp2w  = (const float*)d_in[5];
    const float* lp2b  = (const float*)d_in[6];
    const float* temb  = (const float*)d_in[7];
    const float* ttab  = (const float*)d_in[8];
    const float* tw    = (const float*)d_in[9];
    const float* tb    = (const float*)d_in[10];
    const float* pos   = (const float*)d_in[11];
    const float* qkvw  = (const float*)d_in[12];
    const float* qkvb  = (const float*)d_in[13];
    const float* ow    = (const float*)d_in[14];
    const float* ob    = (const float*)d_in[15];
    const float* ln1g  = (const float*)d_in[16];
    const float* ln1b  = (const float*)d_in[17];
    const float* f1w   = (const float*)d_in[18];
    const float* f1b   = (const float*)d_in[19];
    const float* f2w   = (const float*)d_in[20];
    const float* f2b   = (const float*)d_in[21];
    const float* ln2g  = (const float*)d_in[22];
    const float* ln2b  = (const float*)d_in[23];
    const float* gqw   = (const float*)d_in[24];
    const float* gqb   = (const float*)d_in[25];
    const float* gkw   = (const float*)d_in[26];
    const float* gkb   = (const float*)d_in[27];
    const float* gvw   = (const float*)d_in[28];
    const float* gvb   = (const float*)d_in[29];
    const float* gsw   = (const float*)d_in[30];
    const float* gsb   = (const float*)d_in[31];
    const float* gl1g  = (const float*)d_in[32];
    const float* gl1b  = (const float*)d_in[33];
    const float* gf1w  = (const float*)d_in[34];
    const float* gf1b  = (const float*)d_in[35];
    const float* gf2w  = (const float*)d_in[36];
    const float* gf2b  = (const float*)d_in[37];
    const float* gl2g  = (const float*)d_in[38];
    const float* gl2b  = (const float*)d_in[39];
    const float* nh1w  = (const float*)d_in[40];
    const float* nh1b  = (const float*)d_in[41];
    const float* nh2w  = (const float*)d_in[42];
    const float* nh2b  = (const float*)d_in[43];
    const float* eh1w  = (const float*)d_in[44];
    const float* eh1b  = (const float*)d_in[45];
    const float* eh2w  = (const float*)d_in[46];
    const float* eh2b  = (const float*)d_in[47];
    const float* sh1w  = (const float*)d_in[48];
    const float* sh1b  = (const float*)d_in[49];
    const float* sh2w  = (const float*)d_in[50];
    const float* sh2b  = (const float*)d_in[51];

    float* W = (float*)d_ws;
    MegaArgs A;
    A.z = z; A.tok = tok; A.tt = tt;
    A.lp1w = lp1w; A.lp1b = lp1b; A.lp2w = lp2w; A.lp2b = lp2b;
    A.temb = temb; A.ttab = ttab; A.tw = tw; A.tb = tb; A.pos = pos;
    A.qkvb = qkvb; A.ob = ob; A.ln1g = ln1g; A.ln1b = ln1b;
    A.f1b = f1b; A.f2b = f2b; A.ln2g = ln2g; A.ln2b = ln2b;
    A.gqb = gqb; A.gkb = gkb; A.gvb = gvb; A.gsb = gsb;
    A.gl1g = gl1g; A.gl1b = gl1b; A.gf1b = gf1b; A.gf2b = gf2b;
    A.gl2g = gl2g; A.gl2b = gl2b;
    A.nh1b = nh1b; A.nh2b = nh2b; A.eh1b = eh1b; A.eh2w = eh2w; A.eh2b = eh2b;
    A.sh1w = sh1w; A.sh1b = sh1b; A.sh2w = sh2w; A.sh2b = sh2b;

    A.Hh = W + 0;           A.QK = W + 262144;     A.AO = W + 1310720;
    A.T1 = W + 1572864;     A.HI = W + 1835008;    A.HJ = W + 2097152;
    A.LAT = W + 2359296;    A.TE = W + 2360320;    A.A1 = W + 2361344;
    A.SH = W + 2362368;
    A.MASK = (unsigned char*)(W + 2362880);
    A.wt   = (unsigned short*)(W + 2428416);
    A.bar  = (unsigned*)(W + 4919296);

    float* out = (float*)d_out;
    A.out_node = out; A.out_edge = out + 262144; A.out_sz = out + 524288;

    // weight-transpose table (dstOff in bf16 elems)
    A.ptab.n = 0; unsigned tiles = 0;
    auto add = [&](const float* src, int K, int N, unsigned off) {
        PrepEnt& e = A.ptab.e[A.ptab.n++];
        e.src = src; e.K = K; e.N = N; e.dstOff = off; e.tstart = tiles;
        tiles += (unsigned)((K >> 6) * (N >> 6));
    };
    for (int l = 0; l < 2; ++l) add(qkvw + (size_t)l * 196608, 256, 768,  0 + l * 196608);
    for (int l = 0; l < 2; ++l) add(ow   + (size_t)l * 65536,  256, 256,  393216 + l * 65536);
    for (int l = 0; l < 2; ++l) add(f1w  + (size_t)l * 262144, 256, 1024, 524288 + l * 262144);
    for (int l = 0; l < 2; ++l) add(f2w  + (size_t)l * 262144, 1024, 256, 1048576 + l * 262144);
    for (int l = 0; l < 4; ++l) add(gqw  + (size_t)l * 65536,  256, 256,  1572864 + l * 65536);
    for (int l = 0; l < 4; ++l) add(gkw  + (size_t)l * 65536,  256, 256,  1835008 + l * 65536);
    for (int l = 0; l < 4; ++l) add(gvw  + (size_t)l * 65536,  256, 256,  2097152 + l * 65536);
    for (int l = 0; l < 4; ++l) add(gsw  + (size_t)l * 65536,  256, 256,  2359296 + l * 65536);
    for (int l = 0; l < 4; ++l) add(gf1w + (size_t)l * 262144, 256, 1024, 2621440 + l * 262144);
    for (int l = 0; l < 4; ++l) add(gf2w + (size_t)l * 262144, 1024, 256, 3670016 + l * 262144);
    add(nh1w, 256, 256, 4718592);
    add(nh2w, 256, 256, 4784128);
    add(eh1w,         256, 256, 4849664);
    add(eh1w + 65536, 256, 256, 4915200);

    hipMemsetAsync(A.bar, 0, 8, stream);
    k_mega<<<NB, 256, 0, stream>>>(A);
}

// Round 12
// 810.582 us; speedup vs baseline: 2.7893x; 2.7893x over previous
//
#include <hip/hip_runtime.h>
#include <math.h>

// B=4, N=256, H=256, HEADS=4, DH=64, FF=1024, V=256, L=128, rows BN=1024

typedef __attribute__((ext_vector_type(8))) short bf16x8;
typedef __attribute__((ext_vector_type(4))) float f32x4;

__device__ __forceinline__ unsigned short f2b(float f) {   // f32 -> bf16 RNE
    unsigned u = __float_as_uint(f);
    u += 0x7FFFu + ((u >> 16) & 1u);
    return (unsigned short)(u >> 16);
}
__device__ __forceinline__ unsigned pack2(float a, float b) {
    return (unsigned)f2b(a) | ((unsigned)f2b(b) << 16);
}
__device__ __forceinline__ bf16x8 as_frag(uint4 v) {
    union { uint4 u; bf16x8 f; } x; x.u = v; return x.f;
}
__device__ __forceinline__ bf16x8 ld_frag_f32(const float* p) {  // 8 f32 -> bf16x8
    const float4 v0 = *(const float4*)p;
    const float4 v1 = *(const float4*)(p + 4);
    union { unsigned u[4]; bf16x8 f; } x;
    x.u[0] = pack2(v0.x, v0.y); x.u[1] = pack2(v0.z, v0.w);
    x.u[2] = pack2(v1.x, v1.y); x.u[3] = pack2(v1.z, v1.w);
    return x.f;
}

// Branchless erf-based gelu (A&S 7.1.26, max abs err 1.5e-7).
__device__ __forceinline__ float gelu_f(float x) {
    const float y  = 0.70710678118654752f * x;
    const float ay = fabsf(y);
    const float t  = __builtin_amdgcn_rcpf(fmaf(0.3275911f, ay, 1.0f));
    float S = fmaf(t, 1.061405429f, -1.453152027f);
    S = fmaf(t, S, 1.421413741f);
    S = fmaf(t, S, -0.284496736f);
    S = fmaf(t, S, 0.254829592f);
    S = S * t;
    const float e = __expf(-ay * ay);
    const float E = fmaf(-S, e, 1.0f);
    return 0.5f * x * (1.0f + copysignf(E, y));
}

// ---------------- weight prep table ----------------
struct PrepEnt { const float* src; unsigned dstOff; int K; int N; unsigned tstart; };
struct PrepTab { int n; PrepEnt e[36]; };

struct S0Args {
    const float *z; const int *tok, *tt;
    const float *lp1w,*lp1b,*lp2w,*lp2b,*ttab,*tw,*tb,*temb,*pos;
    const float *sh1w,*sh1b,*sh2w,*sh2b;
    float *Hh, *out_sz;
};

// combo: blocks <1216 transpose+convert one 64x64 weight tile; blocks 1216..1219
// run the full stage-0 chain (lat/te/size head) + embedding for batch b.
__global__ __launch_bounds__(256) void k_combo1(PrepTab tab, unsigned short* __restrict__ wt,
                                                S0Args A)
{
    __shared__ unsigned Tl[64][36];
    __shared__ float zS[256], a1S[256], latS[256], teS[256];
    __shared__ int tokS[256];
    const int bx = blockIdx.x;
    const int tid = threadIdx.x;
    if (bx < 1216) {
        int ei = 0;
        for (int i = 0; i < tab.n; ++i) if (tab.e[i].tstart <= (unsigned)bx) ei = i;
        const PrepEnt E = tab.e[ei];
        const int tIdx = bx - (int)E.tstart;
        const int ntn = E.N >> 6;
        const int kt = tIdx / ntn, nt = tIdx % ntn;
        {
            const int r = tid >> 2, c = (tid & 3) * 16;
            const float* s = E.src + (size_t)(kt * 64 + r) * E.N + nt * 64 + c;
            unsigned o[8];
            #pragma unroll
            for (int q = 0; q < 4; ++q) {
                const float4 v = *(const float4*)(s + q * 4);
                o[q * 2 + 0] = pack2(v.x, v.y);
                o[q * 2 + 1] = pack2(v.z, v.w);
            }
            *(uint4*)&Tl[r][c / 2 + 0] = make_uint4(o[0], o[1], o[2], o[3]);
            *(uint4*)&Tl[r][c / 2 + 4] = make_uint4(o[4], o[5], o[6], o[7]);
        }
        __syncthreads();
        {
            const int rn = tid >> 2, ck = (tid & 3) * 16;
            const int sh = (rn & 1) * 16, hw = rn >> 1;
            unsigned o[8];
            #pragma unroll
            for (int s = 0; s < 8; ++s) {
                const unsigned lo = (Tl[ck + 2 * s][hw] >> sh) & 0xFFFFu;
                const unsigned hi = (Tl[ck + 2 * s + 1][hw] >> sh) & 0xFFFFu;
                o[s] = lo | (hi << 16);
            }
            unsigned short* d = wt + E.dstOff + (size_t)(nt * 64 + rn) * E.K + kt * 64 + ck;
            *(uint4*)(d + 0) = make_uint4(o[0], o[1], o[2], o[3]);
            *(uint4*)(d + 8) = make_uint4(o[4], o[5], o[6], o[7]);
        }
        return;
    }
    // ---- stage 0 for batch b ----
    const int b = bx - 1216;
    const int c = tid;
    if (c < 128) zS[c] = A.z[b * 128 + c];
    teS[c] = A.ttab[(size_t)A.tt[b] * 256 + c];
    tokS[c] = A.tok[b * 256 + c];
    __syncthreads();
    float a1 = A.lp1b[c];
    #pragma unroll 4
    for (int k = 0; k < 128; ++k) a1 = fmaf(zS[k], A.lp1w[k * 256 + c], a1);
    a1 = fmaxf(a1, 0.f);
    float tev = A.tb[c];
    #pragma unroll 4
    for (int k = 0; k < 256; ++k) tev = fmaf(teS[k], A.tw[k * 256 + c], tev);
    __syncthreads();
    a1S[c] = a1;
    teS[c] = gelu_f(tev);
    __syncthreads();
    float lat = A.lp2b[c];
    #pragma unroll 4
    for (int k = 0; k < 256; ++k) lat = fmaf(a1S[k], A.lp2w[k * 256 + c], lat);
    latS[c] = lat;
    __syncthreads();
    if (c < 128) {
        float s = A.sh1b[c];
        #pragma unroll 4
        for (int k = 0; k < 256; ++k) s = fmaf(latS[k], A.sh1w[k * 128 + c], s);
        zS[c] = fmaxf(s, 0.f);
    }
    __syncthreads();
    {
        float v = A.sh2b[c];
        #pragma unroll 4
        for (int k = 0; k < 128; ++k) v = fmaf(zS[k], A.sh2w[k * 256 + c], v);
        A.out_sz[b * 256 + c] = v;
    }
    const float tec = teS[c], lac = latS[c];
    for (int n = 0; n < 256; ++n) {
        A.Hh[(size_t)(b * 256 + n) * 256 + c] =
            A.temb[(size_t)tokS[n] * 256 + c] + tec + A.pos[n * 256 + c] + lac;
    }
}

// ---------------- 32x32 no-LDS MFMA GEMM ----------------
// C = act(A(f32,MxK) @ Wt(bf16,NxK)^T + bias).
// C fragment map: col = n0 + (lane&15), row = m0 + (lane>>4)*4 + reg.
__device__ __forceinline__ void gd32_body(
    const float* __restrict__ A, const unsigned short* __restrict__ Wt,
    const float* __restrict__ bias, float* __restrict__ C,
    int K, int ldc, int act, int m0, int n0)
{
    const int tid = threadIdx.x;
    const int l = tid & 63, wid = tid >> 6;
    const int qm = wid & 1, qn = wid >> 1, lr = l & 15, lg = l >> 4;
    const float* ap = A + (size_t)(m0 + qm * 16 + lr) * K + lg * 8;
    const unsigned short* bp = Wt + (size_t)(n0 + qn * 16 + lr) * K + lg * 8;
    f32x4 acc = {0.f,0.f,0.f,0.f};
    #pragma unroll 4
    for (int k0 = 0; k0 < K; k0 += 32) {
        const bf16x8 fa = ld_frag_f32(ap + k0);
        const bf16x8 fb = as_frag(*(const uint4*)(bp + k0));
        acc = __builtin_amdgcn_mfma_f32_16x16x32_bf16(fa, fb, acc, 0, 0, 0);
    }
    const int cc = n0 + qn * 16 + lr;
    const float bv = bias ? bias[cc] : 0.f;
    #pragma unroll
    for (int r = 0; r < 4; ++r) {
        const int row = m0 + qm * 16 + lg * 4 + r;
        float v = acc[r] + bv;
        if (act == 1) v = fmaxf(v, 0.f); else if (act == 2) v = gelu_f(v);
        C[(size_t)row * ldc + cc] = v;
    }
}

__global__ __launch_bounds__(256) void k_gd32(
    const float* __restrict__ A, const unsigned short* __restrict__ Wt,
    const float* __restrict__ bias, float* __restrict__ C, int K, int ldc, int act)
{
    gd32_body(A, Wt, bias, C, K, ldc, act, blockIdx.y * 32, blockIdx.x * 32);
}

// Batched independent N=256 GEMMs sharing A (z selects entry, up to 4).
struct GBe { const unsigned short* wt; const float* bias; float* C; int ldc; int act; };
struct GB4 { GBe e[4]; };
__global__ __launch_bounds__(256) void k_gd32b(
    const float* __restrict__ A, GB4 p, int K)
{
    const GBe E = p.e[blockIdx.z];
    gd32_body(A, E.wt, E.bias, E.C, K, E.ldc, E.act, blockIdx.y * 32, blockIdx.x * 32);
}

// ---------------- attention: block = (b, head, 16-row group), grid 256 ----------------
__global__ __launch_bounds__(256) void k_attn2(
    const float* __restrict__ qkv, int ld, int qo, int ko, int vo,
    const unsigned char* __restrict__ mask, float* __restrict__ out)
{
    const int blk = blockIdx.x;              // b*64 + hh*16 + ig
    const int ig = blk & 15, hh = (blk >> 4) & 3, b = blk >> 6;
    const int i0 = ig * 16;
    const int t = threadIdx.x;
    __shared__ float Qs[16][68];
    __shared__ float Ts[64][68];
    __shared__ float Ss[16][260];

    {
        const int r = t >> 4, c = (t & 15) * 4;
        *(float4*)&Qs[r][c] = *(const float4*)&qkv[(size_t)(b * 256 + i0 + r) * ld + qo + hh * 64 + c];
    }
    const int i = t >> 4, tx = t & 15;

    for (int jt = 0; jt < 4; ++jt) {
        __syncthreads();
        {
            const int jr = t >> 2, cs = (t & 3) * 16;
            const float* src = &qkv[(size_t)(b * 256 + jt * 64 + jr) * ld + ko + hh * 64 + cs];
            *(float4*)&Ts[jr][cs + 0]  = *(const float4*)(src + 0);
            *(float4*)&Ts[jr][cs + 4]  = *(const float4*)(src + 4);
            *(float4*)&Ts[jr][cs + 8]  = *(const float4*)(src + 8);
            *(float4*)&Ts[jr][cs + 12] = *(const float4*)(src + 12);
        }
        __syncthreads();
        float s0 = 0.f, s1 = 0.f, s2 = 0.f, s3 = 0.f;
        #pragma unroll 8
        for (int d = 0; d < 64; ++d) {
            const float qd = Qs[i][d];
            s0 += qd * Ts[tx][d];
            s1 += qd * Ts[tx + 16][d];
            s2 += qd * Ts[tx + 32][d];
            s3 += qd * Ts[tx + 48][d];
        }
        Ss[i][jt * 64 + tx]      = s0;
        Ss[i][jt * 64 + tx + 16] = s1;
        Ss[i][jt * 64 + tx + 32] = s2;
        Ss[i][jt * 64 + tx + 48] = s3;
    }

    {
        const unsigned char* mrow = mask ? &mask[(size_t)(b * 256 + i0 + i) * 256] : nullptr;
        float sv[16]; bool okv[16];
        float m = -3.0e38f;
        #pragma unroll
        for (int k = 0; k < 16; ++k) {
            const int j = tx + 16 * k;
            const float s = Ss[i][j] * 0.125f;
            const bool ok = mrow ? (mrow[j] != 0) : true;
            sv[k] = s; okv[k] = ok;
            if (ok) m = fmaxf(m, s);
        }
        #pragma unroll
        for (int w = 1; w < 16; w <<= 1) m = fmaxf(m, __shfl_xor(m, w, 64));
        float sum = 0.f;
        #pragma unroll
        for (int k = 0; k < 16; ++k) {
            sv[k] = okv[k] ? __expf(sv[k] - m) : 0.f;
            sum += sv[k];
        }
        #pragma unroll
        for (int w = 1; w < 16; w <<= 1) sum += __shfl_xor(sum, w, 64);
        const float inv = (sum > 0.f) ? 1.f / sum : 0.f;
        #pragma unroll
        for (int k = 0; k < 16; ++k) Ss[i][tx + 16 * k] = sv[k] * inv;
    }

    const int d4 = tx * 4;
    float4 o = {0.f, 0.f, 0.f, 0.f};
    for (int jt = 0; jt < 4; ++jt) {
        __syncthreads();
        {
            const int jr = t >> 2, cs = (t & 3) * 16;
            const float* src = &qkv[(size_t)(b * 256 + jt * 64 + jr) * ld + vo + hh * 64 + cs];
            *(float4*)&Ts[jr][cs + 0]  = *(const float4*)(src + 0);
            *(float4*)&Ts[jr][cs + 4]  = *(const float4*)(src + 4);
            *(float4*)&Ts[jr][cs + 8]  = *(const float4*)(src + 8);
            *(float4*)&Ts[jr][cs + 12] = *(const float4*)(src + 12);
        }
        __syncthreads();
        #pragma unroll 8
        for (int j = 0; j < 64; ++j) {
            const float p = Ss[i][jt * 64 + j];
            const float4 v4 = *(const float4*)&Ts[j][d4];
            o.x += p * v4.x; o.y += p * v4.y; o.z += p * v4.z; o.w += p * v4.w;
        }
    }
    *(float4*)&out[(size_t)(b * 256 + i0 + i) * 256 + hh * 64 + d4] = o;
}

// ---------------- wave-per-row LayerNorm (no LDS, no barriers), grid 256 ----------------
__global__ __launch_bounds__(256) void k_ln2(
    const float* __restrict__ a, const float* __restrict__ bb, int ldb,
    const float* __restrict__ cc, int ldc,
    const float* __restrict__ g, const float* __restrict__ beta, float* __restrict__ out)
{
    const int r = blockIdx.x * 4 + (threadIdx.x >> 6);
    const int c4 = (threadIdx.x & 63) * 4;
    float4 v = *(const float4*)&a[(size_t)r * 256 + c4];
    if (bb) {
        const float4 u = *(const float4*)&bb[(size_t)r * ldb + c4];
        v.x += u.x; v.y += u.y; v.z += u.z; v.w += u.w;
    }
    if (cc) {
        const float4 u = *(const float4*)&cc[(size_t)r * ldc + c4];
        v.x += u.x; v.y += u.y; v.z += u.z; v.w += u.w;
    }
    float s = v.x + v.y + v.z + v.w;
    float q = v.x * v.x + v.y * v.y + v.z * v.z + v.w * v.w;
    #pragma unroll
    for (int w = 1; w < 64; w <<= 1) {
        s += __shfl_xor(s, w, 64);
        q += __shfl_xor(q, w, 64);
    }
    const float mean = s * (1.0f / 256.0f);
    const float var  = q * (1.0f / 256.0f) - mean * mean;
    const float inv  = rsqrtf(var + 1e-5f);
    const float4 gg = *(const float4*)&g[c4];
    const float4 be = *(const float4*)&beta[c4];
    float4 o;
    o.x = (v.x - mean) * inv * gg.x + be.x;
    o.y = (v.y - mean) * inv * gg.y + be.y;
    o.z = (v.z - mean) * inv * gg.z + be.z;
    o.w = (v.w - mean) * inv * gg.w + be.w;
    *(float4*)&out[(size_t)r * 256 + c4] = o;
}

// ---------------- edge logits body: one 16x16 tile ----------------
__device__ __forceinline__ void edge_body(
    const float* __restrict__ hi, const float* __restrict__ hj,
    const float* __restrict__ w2, const float* __restrict__ b2,
    float* __restrict__ val_out, unsigned char* __restrict__ mask_out,
    int b, int ig, int jg, char* SMc)
{
    float (*his)[268] = (float(*)[268])SMc;
    float (*hjs)[268] = (float(*)[268])(SMc + 17152);
    float* w2s = (float*)(SMc + 34304);
    const int t = threadIdx.x;
    {
        const int r = t >> 4, c = (t & 15) * 16;
        const float* s1 = &hi[(size_t)(b * 256 + ig * 16 + r) * 256 + c];
        const float* s2 = &hj[(size_t)(b * 256 + jg * 16 + r) * 256 + c];
        #pragma unroll
        for (int q = 0; q < 4; ++q) {
            *(float4*)&his[r][c + q * 4] = *(const float4*)(s1 + q * 4);
            *(float4*)&hjs[r][c + q * 4] = *(const float4*)(s2 + q * 4);
        }
        w2s[t] = w2[t];
    }
    __syncthreads();
    const int i = t >> 4, j = t & 15;
    float acc = 0.f;
    #pragma unroll 4
    for (int h4 = 0; h4 < 64; ++h4) {
        const float4 hv  = *(const float4*)&hjs[j][h4 * 4];
        const float4 hi4 = *(const float4*)&his[i][h4 * 4];
        const float4 w4  = *(const float4*)&w2s[h4 * 4];
        acc += gelu_f(hi4.x + hv.x) * w4.x;
        acc += gelu_f(hi4.y + hv.y) * w4.y;
        acc += gelu_f(hi4.z + hv.z) * w4.z;
        acc += gelu_f(hi4.w + hv.w) * w4.w;
    }
    const float v = acc + b2[0];
    if (val_out)  val_out[(size_t)b * 65536 + (ig * 16 + i) * 256 + jg * 16 + j] = v;
    if (mask_out) mask_out[(size_t)b * 65536 + (jg * 16 + j) * 256 + ig * 16 + i] =
                      (v > -0.84729786038720f) ? 1 : 0;
}

__global__ __launch_bounds__(256) void k_edge3(
    const float* __restrict__ hi, const float* __restrict__ hj,
    const float* __restrict__ w2, const float* __restrict__ b2,
    float* __restrict__ val_out, unsigned char* __restrict__ mask_out)
{
    __shared__ __align__(16) char SM[35328];
    edge_body(hi, hj, w2, b2, val_out, mask_out,
              blockIdx.z, blockIdx.y, blockIdx.x, SM);
}

// final combo: blocks <1024 = edge tiles -> out_edge; blocks >=1024 = nh2 GEMM tiles.
__global__ __launch_bounds__(256) void k_final(
    const float* __restrict__ hi, const float* __restrict__ hj,
    const float* __restrict__ w2, const float* __restrict__ b2,
    float* __restrict__ out_edge,
    const float* __restrict__ T1, const unsigned short* __restrict__ nh2wt,
    const float* __restrict__ nh2b, float* __restrict__ out_node)
{
    __shared__ __align__(16) char SM[35328];
    const int bx = blockIdx.x;
    if (bx < 1024) {
        edge_body(hi, hj, w2, b2, out_edge, nullptr,
                  bx >> 8, (bx >> 4) & 15, bx & 15, SM);
    } else {
        const int s = bx - 1024;                    // 256 tiles: 32 m x 8 n
        gd32_body(T1, nh2wt, nh2b, out_node, 256, 256, 0, (s & 31) * 32, (s >> 5) * 32);
    }
}

extern "C" void kernel_launch(void* const* d_in, const int* in_sizes, int n_in,
                              void* d_out, int out_size, void* d_ws, size_t ws_size,
                              hipStream_t stream) {
    const float* z     = (const float*)d_in[0];
    const int*   tok   = (const int*)d_in[1];
    const int*   tt    = (const int*)d_in[2];
    const float* lp1w  = (const float*)d_in[3];
    const float* lp1b  = (const float*)d_in[4];
    const float* lp2w  = (const float*)d_in[5];
    const float* lp2b  = (const float*)d_in[6];
    const float* temb  = (const float*)d_in[7];
    const float* ttab  = (const float*)d_in[8];
    const float* tw    = (const float*)d_in[9];
    const float* tb    = (const float*)d_in[10];
    const float* pos   = (const float*)d_in[11];
    const float* qkvw  = (const float*)d_in[12];
    const float* qkvb  = (const float*)d_in[13];
    const float* ow    = (const float*)d_in[14];
    const float* ob    = (const float*)d_in[15];
    const float* ln1g  = (const float*)d_in[16];
    const float* ln1b  = (const float*)d_in[17];
    const float* f1w   = (const float*)d_in[18];
    const float* f1b   = (const float*)d_in[19];
    const float* f2w   = (const float*)d_in[20];
    const float* f2b   = (const float*)d_in[21];
    const float* ln2g  = (const float*)d_in[22];
    const float* ln2b  = (const float*)d_in[23];
    const float* gqw   = (const float*)d_in[24];
    const float* gqb   = (const float*)d_in[25];
    const float* gkw   = (const float*)d_in[26];
    const float* gkb   = (const float*)d_in[27];
    const float* gvw   = (const float*)d_in[28];
    const float* gvb   = (const float*)d_in[29];
    const float* gsw   = (const float*)d_in[30];
    const float* gsb   = (const float*)d_in[31];
    const float* gl1g  = (const float*)d_in[32];
    const float* gl1b  = (const float*)d_in[33];
    const float* gf1w  = (const float*)d_in[34];
    const float* gf1b  = (const float*)d_in[35];
    const float* gf2w  = (const float*)d_in[36];
    const float* gf2b  = (const float*)d_in[37];
    const float* gl2g  = (const float*)d_in[38];
    const float* gl2b  = (const float*)d_in[39];
    const float* nh1w  = (const float*)d_in[40];
    const float* nh1b  = (const float*)d_in[41];
    const float* nh2w  = (const float*)d_in[42];
    const float* nh2b  = (const float*)d_in[43];
    const float* eh1w  = (const float*)d_in[44];
    const float* eh1b  = (const float*)d_in[45];
    const float* eh2w  = (const float*)d_in[46];
    const float* eh2b  = (const float*)d_in[47];
    const float* sh1w  = (const float*)d_in[48];
    const float* sh1b  = (const float*)d_in[49];
    const float* sh2w  = (const float*)d_in[50];
    const float* sh2b  = (const float*)d_in[51];

    float* W = (float*)d_ws;
    float* Hh  = W + 0;          // 262144
    float* QK  = W + 262144;     // 1048576 (qkv / qkvs / ffn hidden)
    float* AO  = W + 1310720;    // 262144
    float* T1  = W + 1572864;    // 262144
    float* HI  = W + 1835008;    // 262144
    float* HJ  = W + 2097152;    // 262144
    unsigned char* MASK = (unsigned char*)(W + 2359296);          // 262144 B
    unsigned short* wt  = (unsigned short*)(W + 2424832);         // bf16 Wt region

    float* out      = (float*)d_out;
    float* out_node = out;
    float* out_edge = out + 262144;
    float* out_sz   = out + 524288;

    // ---- weight-transpose table (offsets in bf16 elems) ----
    PrepTab tab; tab.n = 0; unsigned tiles = 0;
    auto add = [&](const float* src, int K, int N, unsigned off) {
        PrepEnt& e = tab.e[tab.n++];
        e.src = src; e.K = K; e.N = N; e.dstOff = off; e.tstart = tiles;
        tiles += (unsigned)((K >> 6) * (N >> 6));
    };
    for (int l = 0; l < 2; ++l) add(qkvw + (size_t)l * 196608, 256, 768,  0 + l * 196608);
    for (int l = 0; l < 2; ++l) add(ow   + (size_t)l * 65536,  256, 256,  393216 + l * 65536);
    for (int l = 0; l < 2; ++l) add(f1w  + (size_t)l * 262144, 256, 1024, 524288 + l * 262144);
    for (int l = 0; l < 2; ++l) add(f2w  + (size_t)l * 262144, 1024, 256, 1048576 + l * 262144);
    for (int l = 0; l < 4; ++l) add(gqw  + (size_t)l * 65536,  256, 256,  1572864 + l * 65536);
    for (int l = 0; l < 4; ++l) add(gkw  + (size_t)l * 65536,  256, 256,  1835008 + l * 65536);
    for (int l = 0; l < 4; ++l) add(gvw  + (size_t)l * 65536,  256, 256,  2097152 + l * 65536);
    for (int l = 0; l < 4; ++l) add(gsw  + (size_t)l * 65536,  256, 256,  2359296 + l * 65536);
    for (int l = 0; l < 4; ++l) add(gf1w + (size_t)l * 262144, 256, 1024, 2621440 + l * 262144);
    for (int l = 0; l < 4; ++l) add(gf2w + (size_t)l * 262144, 1024, 256, 3670016 + l * 262144);
    add(nh1w, 256, 256, 4718592);
    add(nh2w, 256, 256, 4784128);
    add(eh1w,         256, 256, 4849664);
    add(eh1w + 65536, 256, 256, 4915200);

    S0Args s0;
    s0.z = z; s0.tok = tok; s0.tt = tt;
    s0.lp1w = lp1w; s0.lp1b = lp1b; s0.lp2w = lp2w; s0.lp2b = lp2b;
    s0.ttab = ttab; s0.tw = tw; s0.tb = tb; s0.temb = temb; s0.pos = pos;
    s0.sh1w = sh1w; s0.sh1b = sh1b; s0.sh2w = sh2w; s0.sh2b = sh2b;
    s0.Hh = Hh; s0.out_sz = out_sz;

    // 1) weight prep (1216 blocks) + stage0/embed (4 blocks)
    k_combo1<<<1220, 256, 0, stream>>>(tab, wt, s0);

    // ---- encoder x2 ----
    for (int l = 0; l < 2; ++l) {
        k_gd32<<<dim3(24, 32), 256, 0, stream>>>(Hh, wt + (size_t)l * 196608,
                                                 qkvb + l * 768, QK, 256, 768, 0);
        k_attn2<<<256, 256, 0, stream>>>(QK, 768, 0, 256, 512, nullptr, AO);
        k_gd32<<<dim3(8, 32), 256, 0, stream>>>(AO, wt + 393216 + (size_t)l * 65536,
                                                ob + l * 256, T1, 256, 256, 0);
        k_ln2<<<256, 256, 0, stream>>>(Hh, T1, 256, nullptr, 0,
                                       ln1g + l * 256, ln1b + l * 256, Hh);
        k_gd32<<<dim3(32, 32), 256, 0, stream>>>(Hh, wt + 524288 + (size_t)l * 262144,
                                                 f1b + l * 1024, QK, 256, 1024, 1);
        k_gd32<<<dim3(8, 32), 256, 0, stream>>>(QK, wt + 1048576 + (size_t)l * 262144,
                                                f2b + l * 256, T1, 1024, 256, 0);
        k_ln2<<<256, 256, 0, stream>>>(Hh, T1, 256, nullptr, 0,
                                       ln2g + l * 256, ln2b + l * 256, Hh);
    }

    // ---- mask from el0(h) ----
    {
        GB4 p;
        p.e[0] = { wt + 4849664, eh1b,    HI, 256, 0 };
        p.e[1] = { wt + 4915200, nullptr, HJ, 256, 0 };
        p.e[2] = p.e[0]; p.e[3] = p.e[0];
        k_gd32b<<<dim3(8, 32, 2), 256, 0, stream>>>(Hh, p, 256);
    }
    k_edge3<<<dim3(16, 16, 4), 256, 0, stream>>>(HI, HJ, eh2w, eh2b, nullptr, MASK);

    // ---- GNN x4 ----
    for (int l = 0; l < 4; ++l) {
        GB4 p;
        p.e[0] = { wt + 1572864 + (size_t)l * 65536, gqb + l * 256, QK + 0,   1024, 0 };
        p.e[1] = { wt + 1835008 + (size_t)l * 65536, gkb + l * 256, QK + 256, 1024, 0 };
        p.e[2] = { wt + 2097152 + (size_t)l * 65536, gvb + l * 256, QK + 512, 1024, 0 };
        p.e[3] = { wt + 2359296 + (size_t)l * 65536, gsb + l * 256, QK + 768, 1024, 0 };
        k_gd32b<<<dim3(8, 32, 4), 256, 0, stream>>>(Hh, p, 256);
        k_attn2<<<256, 256, 0, stream>>>(QK, 1024, 0, 256, 512, MASK, AO);
        k_ln2<<<256, 256, 0, stream>>>(Hh, AO, 256, QK + 768, 1024,
                                       gl1g + l * 256, gl1b + l * 256, Hh);
        k_gd32<<<dim3(32, 32), 256, 0, stream>>>(Hh, wt + 2621440 + (size_t)l * 262144,
                                                 gf1b + l * 1024, QK, 256, 1024, 2);
        GB4 q;
        q.e[0] = { wt + 3670016 + (size_t)l * 262144, gf2b + l * 256, T1, 256, 0 };
        q.e[1] = q.e[0]; q.e[2] = q.e[0]; q.e[3] = q.e[0];
        k_gd32b<<<dim3(8, 32, 1), 256, 0, stream>>>(QK, q, 1024);
        k_ln2<<<256, 256, 0, stream>>>(Hh, T1, 256, nullptr, 0,
                                       gl2g + l * 256, gl2b + l * 256, Hh);
    }

    // ---- heads: nh1 / HI / HJ batched, then final (edge + nh2) ----
    {
        GB4 p;
        p.e[0] = { wt + 4718592, nh1b,    T1, 256, 2 };
        p.e[1] = { wt + 4849664, eh1b,    HI, 256, 0 };
        p.e[2] = { wt + 4915200, nullptr, HJ, 256, 0 };
        p.e[3] = p.e[0];
        k_gd32b<<<dim3(8, 32, 3), 256, 0, stream>>>(Hh, p, 256);
    }
    k_final<<<1280, 256, 0, stream>>>(HI, HJ, eh2w, eh2b, out_edge,
                                      T1, wt + 4784128, nh2b, out_node);
}